// Round 10
// baseline (111.087 us; speedup 1.0000x reference)
//
#include <hip/hip_runtime.h>
#include <hip/hip_bf16.h>

#define B_N    8192
#define Z_N    10
#define IN_D   512
#define OUT_D  512
#define R_N    8
#define M_N    3
#define ALPHA  0.04419417382415922f   // 1/sqrt(512), SCALING=1 folded

// ---- grouped-GEMM geometry ----
#define NPC      16                    // nodes per chunk
#define BN       48                    // NPC * 3 columns
#define MAXCH    (B_N / NPC + Z_N)     // 522 worst-case chunks
#define BSTRIDE  1040                  // bytes per B_s column: 512*2 + 16 pad

// Wt tiled layout: [z][kt(16)][row(512)][32 ushorts = 64B covering k=kt*32..+31]

// ---- ws layout (bytes) ----
#define OFF_WT   0u
#define SZ_WT    (Z_N * OUT_D * IN_D * 2u)        // 5,242,880
#define OFF_PERM (OFF_WT + SZ_WT)
#define SZ_PERM  (B_N * 4u)
#define OFF_ZARR (OFF_PERM + SZ_PERM)
#define SZ_ZARR  (B_N * 4u)
#define OFF_PART (OFF_ZARR + SZ_ZARR)
#define SZ_PART  (32u * Z_N * 4u)
#define OFF_TOT  (OFF_PART + SZ_PART)
#define SZ_TOT   (Z_N * 4u)
#define WS_NEED  (OFF_TOT + SZ_TOT)

#define MERGE_BLOCKS (Z_N * OUT_D / 8)  // 640 (8 W-rows per block, A[z] in LDS)
#define ZHIST_BLOCKS (B_N / 256)        // 32

typedef __attribute__((ext_vector_type(8))) short short8v;
typedef __attribute__((ext_vector_type(4))) float float4v;
typedef __attribute__((ext_vector_type(4))) int   int4v;

__device__ __forceinline__ unsigned short f2bf(float f) {
    unsigned int x = __float_as_uint(f);
    x += 0x7fffu + ((x >> 16) & 1u);
    return (unsigned short)(x >> 16);
}
__device__ __forceinline__ float bfbits_lo(unsigned int u) { return __uint_as_float(u << 16); }
__device__ __forceinline__ float bfbits_hi(unsigned int u) { return __uint_as_float(u & 0xffff0000u); }

// packed f32x2 -> bf16x2 (RNE), single VALU op
__device__ __forceinline__ unsigned cvt_pk_bf16(float lo, float hi) {
    unsigned r;
    asm("v_cvt_pk_bf16_f32 %0, %1, %2" : "=v"(r) : "v"(lo), "v"(hi));
    return r;
}

template <typename T>
__device__ __forceinline__ T ntload(const T* p) { return __builtin_nontemporal_load(p); }

// ---------------------------------------------------------------------------
// K1: fused  (a) W-merge -> bf16 TILED Wt, 8 rows/block with A[z] in LDS
//            (b) z-extract + per-block partial histogram (no global atomics)
// ---------------------------------------------------------------------------
__global__ __launch_bounds__(256) void prep_kernel(
    const float* __restrict__ weights, const float* __restrict__ lora_A,
    const float* __restrict__ lora_B, const float* __restrict__ attrs,
    unsigned short* __restrict__ Wt, int* __restrict__ zarr,
    int* __restrict__ part) {
    int bid = blockIdx.x;
    int tid = threadIdx.x;
    if (bid < MERGE_BLOCKS) {
        int r0 = bid * 8;                       // 8 rows, all same z (512%8==0)
        int z = r0 >> 9;
        __shared__ __align__(16) float4 a_s[R_N * 128];   // A[z] fp32, 16 KB
        const float4* A4 = reinterpret_cast<const float4*>(lora_A) + (size_t)z * (R_N * 128);
#pragma unroll
        for (int i = 0; i < 4; ++i) {
            int idx = tid + 256 * i;
            a_s[idx] = A4[idx];
        }
        int row = r0 + (tid >> 5);              // this thread's global row
        int o = row & 511;
        int ql = tid & 31;                      // lane's first q; q_j = ql + 32j
        float lb[R_N];
        const float* bp = lora_B + (size_t)row * R_N;
#pragma unroll
        for (int rr = 0; rr < R_N; ++rr) lb[rr] = bp[rr] * ALPHA;
        __syncthreads();

        const float4* w4 = reinterpret_cast<const float4*>(weights) + (size_t)row * 128;
#pragma unroll
        for (int j = 0; j < 4; ++j) {
            int q = ql + 32 * j;
            float4 wv = w4[q];
            float ax = wv.x * ALPHA, ay = wv.y * ALPHA;
            float az = wv.z * ALPHA, aw = wv.w * ALPHA;
#pragma unroll
            for (int rr = 0; rr < R_N; ++rr) {
                float4 av = a_s[rr * 128 + q];
                ax += av.x * lb[rr]; ay += av.y * lb[rr];
                az += av.z * lb[rr]; aw += av.w * lb[rr];
            }
            ushort4 o4;
            o4.x = f2bf(ax); o4.y = f2bf(ay); o4.z = f2bf(az); o4.w = f2bf(aw);
            size_t byte = ((size_t)z * 8192 + (size_t)(q >> 3) * 512 + o) * 64
                          + (size_t)(q & 7) * 8;
            *reinterpret_cast<ushort4*>(reinterpret_cast<char*>(Wt) + byte) = o4;
        }
    } else {
        __shared__ int h_s[Z_N];
        if (tid < Z_N) h_s[tid] = 0;
        __syncthreads();
        int bl = bid - MERGE_BLOCKS;
        int n = bl * 256 + tid;                 // exactly covers B_N
        const float* a = attrs + (size_t)n * Z_N;
        int z = 0;
#pragma unroll
        for (int zz = 1; zz < Z_N; ++zz)
            if (a[zz] > 0.5f) z = zz;
        zarr[n] = z;
        atomicAdd(&h_s[z], 1);
        __syncthreads();
        if (tid < Z_N) part[bl * Z_N + tid] = h_s[tid];
    }
}

// ---------------------------------------------------------------------------
// K2: deterministic scatter (no global atomics). Block b places its 256
// nodes; bases from partial histograms; block 0 also writes tot[z].
// ---------------------------------------------------------------------------
__global__ __launch_bounds__(256) void scatter_kernel(
    const int* __restrict__ zarr, const int* __restrict__ part,
    int* __restrict__ perm, int* __restrict__ tot) {
    __shared__ int lcnt[Z_N];
    __shared__ int base_s[Z_N];
    int b = blockIdx.x;
    int tid = threadIdx.x;
    if (tid < Z_N) lcnt[tid] = 0;
    __syncthreads();
    int n = b * 256 + tid;
    int z = zarr[n];
    int rank = atomicAdd(&lcnt[z], 1);   // LDS only; intra-z order irrelevant
    if (tid < Z_N) {
        int zq = tid, base = 0, tz = 0;
        for (int bb = 0; bb < ZHIST_BLOCKS; ++bb) {
            for (int zz = 0; zz < zq; ++zz) base += part[bb * Z_N + zz];
            int p = part[bb * Z_N + zq];
            if (bb < b) base += p;
            tz += p;
        }
        base_s[zq] = base;
        if (b == 0) tot[zq] = tz;
    }
    __syncthreads();
    perm[base_s[z] + rank] = n;
}

// ---------------------------------------------------------------------------
// K3: grouped GEMM (r9 structure + cvt_pk staging + NT A-loads + full unroll)
// ---------------------------------------------------------------------------
__global__ __launch_bounds__(512, 2) void gemm_kernel(
    const unsigned short* __restrict__ Wt, const float* __restrict__ t,
    const int* __restrict__ perm, const int* __restrict__ tot,
    float* __restrict__ out) {
    // bijective XCD-aware swizzle over [0, MAXCH)
    int orig = blockIdx.x;
    const int qq = MAXCH >> 3, r8 = MAXCH & 7;
    int xcd = orig & 7, off = orig >> 3;
    int chunk = (xcd < r8 ? xcd * (qq + 1) : r8 * (qq + 1) + (xcd - r8) * qq) + off;

    // chunk table recomputed from tot[10] (scalar, no arrays)
    int z = -1, ns = 0, nn = 0;
    {
        int cum = 0, cc = 0;
#pragma unroll
        for (int zz = 0; zz < Z_N; ++zz) {
            int hz = tot[zz];
            int czz = (hz + NPC - 1) / NPC;
            if (z < 0 && chunk < cc + czz) {
                z = zz;
                int j = (chunk - cc) * NPC;
                ns = cum + j;
                nn = (hz - j < NPC) ? (hz - j) : NPC;
            }
            cum += hz; cc += czz;
        }
        if (chunk >= cc) return;
    }

    __shared__ __align__(16) char B_s[BN * BSTRIDE];   // 49,920 B
    __shared__ int node_ids[NPC];

    int tid = threadIdx.x;
    int lane = tid & 63, wid = tid >> 6;
    int lrow = lane & 15, g = lane >> 4;
    int wrow = wid * 64;

    if (tid < NPC) node_ids[tid] = (tid < nn) ? perm[ns + tid] : -1;

    // ---- stage B: fp32 t -> bf16 via v_cvt_pk, transposed to [col=(n,d)][k] ----
    {
        int n = tid >> 5, grp = tid & 31;       // node slot, k-16-group
        int node = (n < nn) ? perm[ns + n] : -1;
        float f[48];
        if (node >= 0) {
            const float4* tp = reinterpret_cast<const float4*>(
                t + (size_t)node * (IN_D * M_N)) + grp * 12;
#pragma unroll
            for (int j = 0; j < 12; ++j) {
                float4 v = tp[j];
                f[4 * j]     = v.x; f[4 * j + 1] = v.y;
                f[4 * j + 2] = v.z; f[4 * j + 3] = v.w;
            }
        } else {
#pragma unroll
            for (int j = 0; j < 48; ++j) f[j] = 0.f;
        }
#pragma unroll
        for (int d = 0; d < 3; ++d) {
            unsigned u[8];
#pragma unroll
            for (int m = 0; m < 8; ++m)
                u[m] = cvt_pk_bf16(f[3 * (2 * m) + d], f[3 * (2 * m + 1) + d]);
            int4v v0 = (int4v){(int)u[0], (int)u[1], (int)u[2], (int)u[3]};
            int4v v1 = (int4v){(int)u[4], (int)u[5], (int)u[6], (int)u[7]};
            char* base = B_s + (n * 3 + d) * BSTRIDE + grp * 32;
            *reinterpret_cast<int4v*>(base)      = v0;
            *reinterpret_cast<int4v*>(base + 16) = v1;
        }
    }
    __syncthreads();

    float4v acc[4][3];
#pragma unroll
    for (int mi = 0; mi < 4; ++mi)
#pragma unroll
        for (int ni = 0; ni < 3; ++ni) acc[mi][ni] = (float4v){0.f, 0.f, 0.f, 0.f};

    const char* bp0 = B_s + lrow * BSTRIDE + g * 16;
    const unsigned short* aw = Wt + (size_t)z * 262144
                               + (size_t)(wrow + lrow) * 32 + (size_t)g * 8;

#pragma unroll
    for (int kt = 0; kt < 16; ++kt) {
        const unsigned short* ak = aw + kt * 16384;
        short8v a0 = ntload(reinterpret_cast<const short8v*>(ak));
        short8v a1 = ntload(reinterpret_cast<const short8v*>(ak + 512));
        short8v a2 = ntload(reinterpret_cast<const short8v*>(ak + 1024));
        short8v a3 = ntload(reinterpret_cast<const short8v*>(ak + 1536));
        short8v b0 = *reinterpret_cast<const short8v*>(bp0 + 0 * 16 * BSTRIDE + kt * 64);
        short8v b1 = *reinterpret_cast<const short8v*>(bp0 + 1 * 16 * BSTRIDE + kt * 64);
        short8v b2 = *reinterpret_cast<const short8v*>(bp0 + 2 * 16 * BSTRIDE + kt * 64);
        acc[0][0] = __builtin_amdgcn_mfma_f32_16x16x32_bf16(a0, b0, acc[0][0], 0, 0, 0);
        acc[0][1] = __builtin_amdgcn_mfma_f32_16x16x32_bf16(a0, b1, acc[0][1], 0, 0, 0);
        acc[0][2] = __builtin_amdgcn_mfma_f32_16x16x32_bf16(a0, b2, acc[0][2], 0, 0, 0);
        acc[1][0] = __builtin_amdgcn_mfma_f32_16x16x32_bf16(a1, b0, acc[1][0], 0, 0, 0);
        acc[1][1] = __builtin_amdgcn_mfma_f32_16x16x32_bf16(a1, b1, acc[1][1], 0, 0, 0);
        acc[1][2] = __builtin_amdgcn_mfma_f32_16x16x32_bf16(a1, b2, acc[1][2], 0, 0, 0);
        acc[2][0] = __builtin_amdgcn_mfma_f32_16x16x32_bf16(a2, b0, acc[2][0], 0, 0, 0);
        acc[2][1] = __builtin_amdgcn_mfma_f32_16x16x32_bf16(a2, b1, acc[2][1], 0, 0, 0);
        acc[2][2] = __builtin_amdgcn_mfma_f32_16x16x32_bf16(a2, b2, acc[2][2], 0, 0, 0);
        acc[3][0] = __builtin_amdgcn_mfma_f32_16x16x32_bf16(a3, b0, acc[3][0], 0, 0, 0);
        acc[3][1] = __builtin_amdgcn_mfma_f32_16x16x32_bf16(a3, b1, acc[3][1], 0, 0, 0);
        acc[3][2] = __builtin_amdgcn_mfma_f32_16x16x32_bf16(a3, b2, acc[3][2], 0, 0, 0);
    }

    // ---- epilogue: acc -> LDS (rounds of 4 waves) -> coalesced NT stores ----
    // C/D layout: col = lane&15 (B col), row-in-frag = g*4+e (m89-verified)
#pragma unroll
    for (int r = 0; r < 2; ++r) {
        __syncthreads();                      // B_s free / prev round done
        if ((wid >> 2) == r) {
            int widr = wid & 3;               // rows widr*64.. within round
#pragma unroll
            for (int mi = 0; mi < 4; ++mi)
#pragma unroll
                for (int ni = 0; ni < 3; ++ni) {
                    int col = ni * 16 + lrow;
                    int rl = widr * 64 + mi * 16 + g * 4;
                    *reinterpret_cast<float4v*>(B_s + col * BSTRIDE + rl * 4) = acc[mi][ni];
                }
        }
        __syncthreads();
        // read out-linear: per node 256 rows x 3 d = 192 float4
#pragma unroll
        for (int it = 0; it < 6; ++it) {
            int fi = tid + it * 512;          // < 3072
            int node = fi / 192;
            int s = fi - node * 192;
            int nid = node_ids[node];
            if (nid < 0) continue;
            float4v v;
#pragma unroll
            for (int j = 0; j < 4; ++j) {
                int e = 4 * s + j;            // e < 768
                int rl = e / 3;
                int d = e - 3 * rl;
                v[j] = *reinterpret_cast<const float*>(
                    B_s + (3 * node + d) * BSTRIDE + rl * 4);
            }
            float* op = out + (size_t)nid * (OUT_D * M_N) + r * 768 + 4 * s;
            __builtin_nontemporal_store(v, reinterpret_cast<float4v*>(op));
        }
    }
}

// ---------------------------------------------------------------------------
// Fallback (round-1 path) if ws is too small — row-major Wbf layout
// ---------------------------------------------------------------------------
__global__ __launch_bounds__(256) void merge_w_kernel(
    const float* __restrict__ weights, const float* __restrict__ lora_A,
    const float* __restrict__ lora_B, unsigned short* __restrict__ Wbf) {
    int zo = blockIdx.x;
    int z = zo >> 9;
    int o = zo & (OUT_D - 1);
    int tid = threadIdx.x;
    float lb[R_N];
    const float* bp = lora_B + ((size_t)z * OUT_D + o) * R_N;
#pragma unroll
    for (int r = 0; r < R_N; ++r) lb[r] = bp[r];
    const float* ap = lora_A + (size_t)z * R_N * IN_D;
    const float* wp = weights + ((size_t)z * OUT_D + o) * IN_D;
    unsigned short* op = Wbf + ((size_t)z * OUT_D + o) * IN_D;
    for (int i = tid; i < IN_D; i += 256) {
        float acc = wp[i];
#pragma unroll
        for (int r = 0; r < R_N; ++r) acc += ap[r * IN_D + i] * lb[r];
        op[i] = f2bf(acc * ALPHA);
    }
}

__global__ __launch_bounds__(256) void apply_kernel(
    const float* __restrict__ t, const float* __restrict__ attrs,
    const unsigned short* __restrict__ Wbf, float* __restrict__ out) {
    int b = blockIdx.x;
    int tid = threadIdx.x;
    const float* ab = attrs + (size_t)b * Z_N;
    int z = 0;
#pragma unroll
    for (int zz = 1; zz < Z_N; ++zz)
        if (ab[zz] > 0.5f) z = zz;
    __shared__ __align__(16) float t_s[IN_D * M_N];
    const float* tb = t + (size_t)b * (IN_D * M_N);
    for (int k = tid; k < IN_D * M_N; k += 256) t_s[k] = tb[k];
    __syncthreads();
    const unsigned short* w0 = Wbf + ((size_t)z * OUT_D + tid) * IN_D;
    const unsigned short* w1 = w0 + 256 * IN_D;
    float acc0[M_N] = {0.f, 0.f, 0.f};
    float acc1[M_N] = {0.f, 0.f, 0.f};
    for (int c = 0; c < IN_D; c += 8) {
        uint4 u0 = *reinterpret_cast<const uint4*>(w0 + c);
        uint4 u1 = *reinterpret_cast<const uint4*>(w1 + c);
        float wf0[8], wf1[8];
        unsigned int a0[4] = {u0.x, u0.y, u0.z, u0.w};
        unsigned int a1[4] = {u1.x, u1.y, u1.z, u1.w};
#pragma unroll
        for (int q = 0; q < 4; ++q) {
            wf0[2 * q] = bfbits_lo(a0[q]); wf0[2 * q + 1] = bfbits_hi(a0[q]);
            wf1[2 * q] = bfbits_lo(a1[q]); wf1[2 * q + 1] = bfbits_hi(a1[q]);
        }
        float tf[24];
        const float4* tv = reinterpret_cast<const float4*>(t_s + c * M_N);
#pragma unroll
        for (int q = 0; q < 6; ++q) {
            float4 v = tv[q];
            tf[4 * q] = v.x; tf[4 * q + 1] = v.y; tf[4 * q + 2] = v.z; tf[4 * q + 3] = v.w;
        }
#pragma unroll
        for (int cc = 0; cc < 8; ++cc)
#pragma unroll
            for (int d = 0; d < M_N; ++d) {
                acc0[d] += wf0[cc] * tf[cc * M_N + d];
                acc1[d] += wf1[cc] * tf[cc * M_N + d];
            }
    }
    float* ob = out + (size_t)b * (OUT_D * M_N);
#pragma unroll
    for (int d = 0; d < M_N; ++d) ob[tid * M_N + d] = acc0[d];
#pragma unroll
    for (int d = 0; d < M_N; ++d) ob[(tid + 256) * M_N + d] = acc1[d];
}

extern "C" void kernel_launch(void* const* d_in, const int* in_sizes, int n_in,
                              void* d_out, int out_size, void* d_ws, size_t ws_size,
                              hipStream_t stream) {
    const float* t       = (const float*)d_in[0];
    const float* attrs   = (const float*)d_in[1];
    const float* weights = (const float*)d_in[2];
    const float* lora_A  = (const float*)d_in[3];
    const float* lora_B  = (const float*)d_in[4];
    float* out = (float*)d_out;
    char* ws = (char*)d_ws;

    if (ws_size >= WS_NEED) {
        unsigned short* Wt = (unsigned short*)(ws + OFF_WT);
        int* perm = (int*)(ws + OFF_PERM);
        int* zarr = (int*)(ws + OFF_ZARR);
        int* part = (int*)(ws + OFF_PART);
        int* tot  = (int*)(ws + OFF_TOT);

        prep_kernel<<<MERGE_BLOCKS + ZHIST_BLOCKS, 256, 0, stream>>>(
            weights, lora_A, lora_B, attrs, Wt, zarr, part);
        scatter_kernel<<<ZHIST_BLOCKS, 256, 0, stream>>>(zarr, part, perm, tot);
        gemm_kernel<<<MAXCH, 512, 0, stream>>>(Wt, t, perm, tot, out);
    } else if (ws_size >= SZ_WT) {
        unsigned short* Wbf = (unsigned short*)(ws + OFF_WT);
        merge_w_kernel<<<Z_N * OUT_D, 256, 0, stream>>>(weights, lora_A, lora_B, Wbf);
        apply_kernel<<<B_N, 256, 0, stream>>>(t, attrs, Wbf, out);
    }
}

// Round 11
// 76.794 us; speedup vs baseline: 1.4466x; 1.4466x over previous
//
#include <hip/hip_runtime.h>
#include <hip/hip_bf16.h>

#define B_N    8192
#define Z_N    10
#define IN_D   512
#define OUT_D  512
#define R_N    8
#define M_N    3
#define ALPHA  0.04419417382415922f   // 1/sqrt(512), SCALING=1 folded

// ---- grouped-GEMM geometry ----
#define NPC      32                    // nodes per chunk
#define BN       96                    // NPC * 3 columns
#define MAXCH    (B_N / NPC + Z_N)     // 266 worst-case chunks
#define BSTRIDE  1040                  // bytes per B_s column: 512*2 + 16 pad

// Wt tiled layout: [z][kt(16)][row(512)][32 ushorts = 64B covering k=kt*32..+31]

// ---- ws layout (bytes) ----
#define OFF_WT   0u
#define SZ_WT    (Z_N * OUT_D * IN_D * 2u)        // 5,242,880
#define OFF_PERM (OFF_WT + SZ_WT)
#define SZ_PERM  (B_N * 4u)
#define OFF_ZARR (OFF_PERM + SZ_PERM)
#define SZ_ZARR  (B_N * 4u)
#define OFF_PART (OFF_ZARR + SZ_ZARR)
#define SZ_PART  (32u * Z_N * 4u)
#define OFF_TOT  (OFF_PART + SZ_PART)
#define SZ_TOT   (Z_N * 4u)
#define WS_NEED  (OFF_TOT + SZ_TOT)

#define MERGE_BLOCKS (Z_N * OUT_D / 8)  // 640 (8 W-rows per block, A[z] in LDS)
#define ZHIST_BLOCKS (B_N / 256)        // 32

typedef __attribute__((ext_vector_type(8))) short short8v;
typedef __attribute__((ext_vector_type(4))) float float4v;
typedef __attribute__((ext_vector_type(4))) int   int4v;

__device__ __forceinline__ unsigned short f2bf(float f) {
    unsigned int x = __float_as_uint(f);
    x += 0x7fffu + ((x >> 16) & 1u);
    return (unsigned short)(x >> 16);
}
__device__ __forceinline__ float bfbits_lo(unsigned int u) { return __uint_as_float(u << 16); }
__device__ __forceinline__ float bfbits_hi(unsigned int u) { return __uint_as_float(u & 0xffff0000u); }

// packed f32x2 -> bf16x2 (RNE), single VALU op
__device__ __forceinline__ unsigned cvt_pk_bf16(float lo, float hi) {
    unsigned r;
    asm("v_cvt_pk_bf16_f32 %0, %1, %2" : "=v"(r) : "v"(lo), "v"(hi));
    return r;
}

// ---------------------------------------------------------------------------
// K1: fused  (a) W-merge -> bf16 TILED Wt, 8 rows/block with A[z] in LDS
//            (b) z-extract + per-block partial histogram (no global atomics)
// ---------------------------------------------------------------------------
__global__ __launch_bounds__(256) void prep_kernel(
    const float* __restrict__ weights, const float* __restrict__ lora_A,
    const float* __restrict__ lora_B, const float* __restrict__ attrs,
    unsigned short* __restrict__ Wt, int* __restrict__ zarr,
    int* __restrict__ part) {
    int bid = blockIdx.x;
    int tid = threadIdx.x;
    if (bid < MERGE_BLOCKS) {
        int r0 = bid * 8;                       // 8 rows, all same z (512%8==0)
        int z = r0 >> 9;
        __shared__ __align__(16) float4 a_s[R_N * 128];   // A[z] fp32, 16 KB
        const float4* A4 = reinterpret_cast<const float4*>(lora_A) + (size_t)z * (R_N * 128);
#pragma unroll
        for (int i = 0; i < 4; ++i) {
            int idx = tid + 256 * i;
            a_s[idx] = A4[idx];
        }
        int row = r0 + (tid >> 5);              // this thread's global row
        int o = row & 511;
        int ql = tid & 31;                      // lane's first q; q_j = ql + 32j
        float lb[R_N];
        const float* bp = lora_B + (size_t)row * R_N;
#pragma unroll
        for (int rr = 0; rr < R_N; ++rr) lb[rr] = bp[rr] * ALPHA;
        __syncthreads();

        const float4* w4 = reinterpret_cast<const float4*>(weights) + (size_t)row * 128;
#pragma unroll
        for (int j = 0; j < 4; ++j) {
            int q = ql + 32 * j;
            float4 wv = w4[q];
            float ax = wv.x * ALPHA, ay = wv.y * ALPHA;
            float az = wv.z * ALPHA, aw = wv.w * ALPHA;
#pragma unroll
            for (int rr = 0; rr < R_N; ++rr) {
                float4 av = a_s[rr * 128 + q];
                ax += av.x * lb[rr]; ay += av.y * lb[rr];
                az += av.z * lb[rr]; aw += av.w * lb[rr];
            }
            ushort4 o4;
            o4.x = f2bf(ax); o4.y = f2bf(ay); o4.z = f2bf(az); o4.w = f2bf(aw);
            size_t byte = ((size_t)z * 8192 + (size_t)(q >> 3) * 512 + o) * 64
                          + (size_t)(q & 7) * 8;
            *reinterpret_cast<ushort4*>(reinterpret_cast<char*>(Wt) + byte) = o4;
        }
    } else {
        __shared__ int h_s[Z_N];
        if (tid < Z_N) h_s[tid] = 0;
        __syncthreads();
        int bl = bid - MERGE_BLOCKS;
        int n = bl * 256 + tid;                 // exactly covers B_N
        const float* a = attrs + (size_t)n * Z_N;
        int z = 0;
#pragma unroll
        for (int zz = 1; zz < Z_N; ++zz)
            if (a[zz] > 0.5f) z = zz;
        zarr[n] = z;
        atomicAdd(&h_s[z], 1);
        __syncthreads();
        if (tid < Z_N) part[bl * Z_N + tid] = h_s[tid];
    }
}

// ---------------------------------------------------------------------------
// K2: deterministic scatter (no global atomics). Block b places its 256
// nodes; bases from partial histograms; block 0 also writes tot[z].
// ---------------------------------------------------------------------------
__global__ __launch_bounds__(256) void scatter_kernel(
    const int* __restrict__ zarr, const int* __restrict__ part,
    int* __restrict__ perm, int* __restrict__ tot) {
    __shared__ int lcnt[Z_N];
    __shared__ int base_s[Z_N];
    int b = blockIdx.x;
    int tid = threadIdx.x;
    if (tid < Z_N) lcnt[tid] = 0;
    __syncthreads();
    int n = b * 256 + tid;
    int z = zarr[n];
    int rank = atomicAdd(&lcnt[z], 1);   // LDS only; intra-z order irrelevant
    if (tid < Z_N) {
        int zq = tid, base = 0, tz = 0;
        for (int bb = 0; bb < ZHIST_BLOCKS; ++bb) {
            for (int zz = 0; zz < zq; ++zz) base += part[bb * Z_N + zz];
            int p = part[bb * Z_N + zq];
            if (bb < b) base += p;
            tz += p;
        }
        base_s[zq] = base;
        if (b == 0) tot[zq] = tz;
    }
    __syncthreads();
    perm[base_s[z] + rank] = n;
}

// ---------------------------------------------------------------------------
// K3: grouped GEMM, NPC=32: one block = 32 same-z nodes (96 cols), full
// M=512, 512 threads = 8 waves, each 64 rows x 96 cols (4x6 mfma fragments).
// Halves A-side L2 traffic vs NPC=16 and doubles MFMA per A-load.
// B staged once in ~100KB LDS (cvt_pk); A direct from tiled Wt (plain loads,
// plain loop -- r10's ntload/unroll regression reverted).
// ---------------------------------------------------------------------------
__global__ __launch_bounds__(512) void gemm_kernel(
    const unsigned short* __restrict__ Wt, const float* __restrict__ t,
    const int* __restrict__ perm, const int* __restrict__ tot,
    float* __restrict__ out) {
    // bijective XCD-aware swizzle over [0, MAXCH)
    int orig = blockIdx.x;
    const int qq = MAXCH >> 3, r8 = MAXCH & 7;
    int xcd = orig & 7, off = orig >> 3;
    int chunk = (xcd < r8 ? xcd * (qq + 1) : r8 * (qq + 1) + (xcd - r8) * qq) + off;

    // chunk table recomputed from tot[10] (scalar, no arrays)
    int z = -1, ns = 0, nn = 0;
    {
        int cum = 0, cc = 0;
#pragma unroll
        for (int zz = 0; zz < Z_N; ++zz) {
            int hz = tot[zz];
            int czz = (hz + NPC - 1) / NPC;
            if (z < 0 && chunk < cc + czz) {
                z = zz;
                int j = (chunk - cc) * NPC;
                ns = cum + j;
                nn = (hz - j < NPC) ? (hz - j) : NPC;
            }
            cum += hz; cc += czz;
        }
        if (chunk >= cc) return;
    }

    __shared__ __align__(16) char B_s[BN * BSTRIDE];   // 99,840 B
    __shared__ int node_ids[NPC];

    int tid = threadIdx.x;
    int lane = tid & 63, wid = tid >> 6;
    int lrow = lane & 15, g = lane >> 4;
    int wrow = wid * 64;

    if (tid < NPC) node_ids[tid] = (tid < nn) ? perm[ns + tid] : -1;

    // ---- stage B: fp32 t -> bf16 via v_cvt_pk, transposed to [col=(n,d)][k]
    //      thread (n=tid>>4, grp=tid&15) covers node n, k in [grp*32,grp*32+32)
    {
        int n = tid >> 4, grp = tid & 15;
        int node = (n < nn) ? perm[ns + n] : -1;
#pragma unroll
        for (int h = 0; h < 2; ++h) {           // two k-16 halves
            float f[48];
            if (node >= 0) {
                const float4* tp = reinterpret_cast<const float4*>(
                    t + (size_t)node * (IN_D * M_N)) + grp * 24 + h * 12;
#pragma unroll
                for (int j = 0; j < 12; ++j) {
                    float4 v = tp[j];
                    f[4 * j]     = v.x; f[4 * j + 1] = v.y;
                    f[4 * j + 2] = v.z; f[4 * j + 3] = v.w;
                }
            } else {
#pragma unroll
                for (int j = 0; j < 48; ++j) f[j] = 0.f;
            }
#pragma unroll
            for (int d = 0; d < 3; ++d) {
                unsigned u[8];
#pragma unroll
                for (int m = 0; m < 8; ++m)
                    u[m] = cvt_pk_bf16(f[3 * (2 * m) + d], f[3 * (2 * m + 1) + d]);
                int4v v0 = (int4v){(int)u[0], (int)u[1], (int)u[2], (int)u[3]};
                int4v v1 = (int4v){(int)u[4], (int)u[5], (int)u[6], (int)u[7]};
                char* base = B_s + (n * 3 + d) * BSTRIDE + grp * 64 + h * 32;
                *reinterpret_cast<int4v*>(base)      = v0;
                *reinterpret_cast<int4v*>(base + 16) = v1;
            }
        }
    }
    __syncthreads();

    float4v acc[4][6];
#pragma unroll
    for (int mi = 0; mi < 4; ++mi)
#pragma unroll
        for (int ni = 0; ni < 6; ++ni) acc[mi][ni] = (float4v){0.f, 0.f, 0.f, 0.f};

    const char* bp0 = B_s + lrow * BSTRIDE + g * 16;
    const unsigned short* aw = Wt + (size_t)z * 262144
                               + (size_t)(wrow + lrow) * 32 + (size_t)g * 8;

    for (int kt = 0; kt < 16; ++kt) {
        const unsigned short* ak = aw + kt * 16384;
        short8v a0 = *reinterpret_cast<const short8v*>(ak);
        short8v a1 = *reinterpret_cast<const short8v*>(ak + 512);
        short8v a2 = *reinterpret_cast<const short8v*>(ak + 1024);
        short8v a3 = *reinterpret_cast<const short8v*>(ak + 1536);
        short8v b[6];
#pragma unroll
        for (int ni = 0; ni < 6; ++ni)
            b[ni] = *reinterpret_cast<const short8v*>(bp0 + ni * 16 * BSTRIDE + kt * 64);
#pragma unroll
        for (int ni = 0; ni < 6; ++ni) {
            acc[0][ni] = __builtin_amdgcn_mfma_f32_16x16x32_bf16(a0, b[ni], acc[0][ni], 0, 0, 0);
            acc[1][ni] = __builtin_amdgcn_mfma_f32_16x16x32_bf16(a1, b[ni], acc[1][ni], 0, 0, 0);
            acc[2][ni] = __builtin_amdgcn_mfma_f32_16x16x32_bf16(a2, b[ni], acc[2][ni], 0, 0, 0);
            acc[3][ni] = __builtin_amdgcn_mfma_f32_16x16x32_bf16(a3, b[ni], acc[3][ni], 0, 0, 0);
        }
    }

    // ---- epilogue: acc -> LDS (2 rounds of 4 waves) -> coalesced NT stores ----
    // C/D layout: col = lane&15 (B col), row-in-frag = g*4+e (m89-verified)
#pragma unroll
    for (int r = 0; r < 2; ++r) {
        __syncthreads();                      // B_s free / prev round done
        if ((wid >> 2) == r) {
            int widr = wid & 3;               // rows widr*64.. within round
#pragma unroll
            for (int mi = 0; mi < 4; ++mi)
#pragma unroll
                for (int ni = 0; ni < 6; ++ni) {
                    int col = ni * 16 + lrow;
                    int rl = widr * 64 + mi * 16 + g * 4;
                    *reinterpret_cast<float4v*>(B_s + col * BSTRIDE + rl * 4) = acc[mi][ni];
                }
        }
        __syncthreads();
        // read out-linear: per node 256 rows x 3 d = 192 float4; 32 nodes
#pragma unroll
        for (int it = 0; it < 12; ++it) {
            int fi = tid + it * 512;          // < 6144
            int node = fi / 192;
            int s = fi - node * 192;
            int nid = node_ids[node];
            if (nid < 0) continue;
            float4v v;
#pragma unroll
            for (int j = 0; j < 4; ++j) {
                int e = 4 * s + j;            // e < 768
                int rl = e / 3;
                int d = e - 3 * rl;
                v[j] = *reinterpret_cast<const float*>(
                    B_s + (3 * node + d) * BSTRIDE + rl * 4);
            }
            float* op = out + (size_t)nid * (OUT_D * M_N) + r * 768 + 4 * s;
            __builtin_nontemporal_store(v, reinterpret_cast<float4v*>(op));
        }
    }
}

// ---------------------------------------------------------------------------
// Fallback (round-1 path) if ws is too small — row-major Wbf layout
// ---------------------------------------------------------------------------
__global__ __launch_bounds__(256) void merge_w_kernel(
    const float* __restrict__ weights, const float* __restrict__ lora_A,
    const float* __restrict__ lora_B, unsigned short* __restrict__ Wbf) {
    int zo = blockIdx.x;
    int z = zo >> 9;
    int o = zo & (OUT_D - 1);
    int tid = threadIdx.x;
    float lb[R_N];
    const float* bp = lora_B + ((size_t)z * OUT_D + o) * R_N;
#pragma unroll
    for (int r = 0; r < R_N; ++r) lb[r] = bp[r];
    const float* ap = lora_A + (size_t)z * R_N * IN_D;
    const float* wp = weights + ((size_t)z * OUT_D + o) * IN_D;
    unsigned short* op = Wbf + ((size_t)z * OUT_D + o) * IN_D;
    for (int i = tid; i < IN_D; i += 256) {
        float acc = wp[i];
#pragma unroll
        for (int r = 0; r < R_N; ++r) acc += ap[r * IN_D + i] * lb[r];
        op[i] = f2bf(acc * ALPHA);
    }
}

__global__ __launch_bounds__(256) void apply_kernel(
    const float* __restrict__ t, const float* __restrict__ attrs,
    const unsigned short* __restrict__ Wbf, float* __restrict__ out) {
    int b = blockIdx.x;
    int tid = threadIdx.x;
    const float* ab = attrs + (size_t)b * Z_N;
    int z = 0;
#pragma unroll
    for (int zz = 1; zz < Z_N; ++zz)
        if (ab[zz] > 0.5f) z = zz;
    __shared__ __align__(16) float t_s[IN_D * M_N];
    const float* tb = t + (size_t)b * (IN_D * M_N);
    for (int k = tid; k < IN_D * M_N; k += 256) t_s[k] = tb[k];
    __syncthreads();
    const unsigned short* w0 = Wbf + ((size_t)z * OUT_D + tid) * IN_D;
    const unsigned short* w1 = w0 + 256 * IN_D;
    float acc0[M_N] = {0.f, 0.f, 0.f};
    float acc1[M_N] = {0.f, 0.f, 0.f};
    for (int c = 0; c < IN_D; c += 8) {
        uint4 u0 = *reinterpret_cast<const uint4*>(w0 + c);
        uint4 u1 = *reinterpret_cast<const uint4*>(w1 + c);
        float wf0[8], wf1[8];
        unsigned int a0[4] = {u0.x, u0.y, u0.z, u0.w};
        unsigned int a1[4] = {u1.x, u1.y, u1.z, u1.w};
#pragma unroll
        for (int q = 0; q < 4; ++q) {
            wf0[2 * q] = bfbits_lo(a0[q]); wf0[2 * q + 1] = bfbits_hi(a0[q]);
            wf1[2 * q] = bfbits_lo(a1[q]); wf1[2 * q + 1] = bfbits_hi(a1[q]);
        }
        float tf[24];
        const float4* tv = reinterpret_cast<const float4*>(t_s + c * M_N);
#pragma unroll
        for (int q = 0; q < 6; ++q) {
            float4 v = tv[q];
            tf[4 * q] = v.x; tf[4 * q + 1] = v.y; tf[4 * q + 2] = v.z; tf[4 * q + 3] = v.w;
        }
#pragma unroll
        for (int cc = 0; cc < 8; ++cc)
#pragma unroll
            for (int d = 0; d < M_N; ++d) {
                acc0[d] += wf0[cc] * tf[cc * M_N + d];
                acc1[d] += wf1[cc] * tf[cc * M_N + d];
            }
    }
    float* ob = out + (size_t)b * (OUT_D * M_N);
#pragma unroll
    for (int d = 0; d < M_N; ++d) ob[tid * M_N + d] = acc0[d];
#pragma unroll
    for (int d = 0; d < M_N; ++d) ob[(tid + 256) * M_N + d] = acc1[d];
}

extern "C" void kernel_launch(void* const* d_in, const int* in_sizes, int n_in,
                              void* d_out, int out_size, void* d_ws, size_t ws_size,
                              hipStream_t stream) {
    const float* t       = (const float*)d_in[0];
    const float* attrs   = (const float*)d_in[1];
    const float* weights = (const float*)d_in[2];
    const float* lora_A  = (const float*)d_in[3];
    const float* lora_B  = (const float*)d_in[4];
    float* out = (float*)d_out;
    char* ws = (char*)d_ws;

    if (ws_size >= WS_NEED) {
        unsigned short* Wt = (unsigned short*)(ws + OFF_WT);
        int* perm = (int*)(ws + OFF_PERM);
        int* zarr = (int*)(ws + OFF_ZARR);
        int* part = (int*)(ws + OFF_PART);
        int* tot  = (int*)(ws + OFF_TOT);

        prep_kernel<<<MERGE_BLOCKS + ZHIST_BLOCKS, 256, 0, stream>>>(
            weights, lora_A, lora_B, attrs, Wt, zarr, part);
        scatter_kernel<<<ZHIST_BLOCKS, 256, 0, stream>>>(zarr, part, perm, tot);
        gemm_kernel<<<MAXCH, 512, 0, stream>>>(Wt, t, perm, tot, out);
    } else if (ws_size >= SZ_WT) {
        unsigned short* Wbf = (unsigned short*)(ws + OFF_WT);
        merge_w_kernel<<<Z_N * OUT_D, 256, 0, stream>>>(weights, lora_A, lora_B, Wbf);
        apply_kernel<<<B_N, 256, 0, stream>>>(t, attrs, Wbf, out);
    }
}